// Round 17
// baseline (212.952 us; speedup 1.0000x reference)
//
#include <hip/hip_runtime.h>
#include <hip/hip_fp16.h>
#include <math.h>

#define DEMB 128
#define DHID 64
#define DOUT 32
#define BAG  10
#define NR   3       // src-range phases (L2-slice locality)
#define CAPR 32      // adjacency capacity per (node, range); Poisson(5.33)
#define ROWI (NR * CAPR)   // 96 ints per node
#define BKB  7       // fine bucket = dst >> 7 (128 nodes)
#define BKN  128
#define EBLK 8192    // edges per partition block (256 thr x 32); nblk <= 256
#define MAXBKT 1024
#define GROWS 16     // rows per gemm block (bf16 W1 LDS tile, 16 threads/row)

typedef unsigned int   u32;
typedef unsigned short u16;

__device__ __forceinline__ u16 f2bf(float f) {
    union { float f; u32 i; } c; c.f = f;
    u32 r = c.i + 0x7FFFu + ((c.i >> 16) & 1u);
    return (u16)(r >> 16);
}
__device__ __forceinline__ void bf2x(u32 v, float& lo, float& hi) {
    union { u32 i; float f; } a, b;
    a.i = v << 16; b.i = v & 0xFFFF0000u;
    lo = a.f; hi = b.f;
}
__device__ __forceinline__ u32 pack2(float f0, float f1) {
    return (u32)f2bf(f0) | ((u32)f2bf(f1) << 16);
}
// fp16 helpers (packed half2 in u32)
__device__ __forceinline__ float2 h2f2(u32 v) {
    __half2 h; *reinterpret_cast<u32*>(&h) = v;
    return __half22float2(h);
}
__device__ __forceinline__ u32 f2h2(float a, float b) {
    __half2 h = __floats2half2_rn(a, b);
    return *reinterpret_cast<u32*>(&h);
}
__device__ __forceinline__ u32 hadd2u(u32 a, u32 b) {
    __half2 ha, hb;
    *reinterpret_cast<u32*>(&ha) = a;
    *reinterpret_cast<u32*>(&hb) = b;
    __half2 r = __hadd2(ha, hb);
    return *reinterpret_cast<u32*>(&r);
}
__device__ __forceinline__ u32 hmul2u(u32 a, __half2 s) {
    __half2 ha; *reinterpret_cast<u32*>(&ha) = a;
    __half2 r = __hmul2(ha, s);
    return *reinterpret_cast<u32*>(&r);
}
__device__ __forceinline__ uint4 hadd2u4(uint4 a, uint4 b) {
    a.x = hadd2u(a.x, b.x); a.y = hadd2u(a.y, b.y);
    a.z = hadd2u(a.z, b.z); a.w = hadd2u(a.w, b.w);
    return a;
}

// ---------------------------------------------------------------------------
// K1: role split.
//   blocks [0, nblk)  : passA histogram — counts[bucket][blk] via LDS
//   blocks [nblk, ..) : gemm_table — tableW = emb_table @ W1 (fp16 out).
__global__ __launch_bounds__(256) void histA_gemm(const int* __restrict__ dst, int E,
                                                  int* __restrict__ counts, int nblk, int nbkt,
                                                  const float* __restrict__ T,
                                                  const float* __restrict__ W1,
                                                  u16* __restrict__ TW, int V) {
    __shared__ u32 shbuf[DEMB * DHID / 2];          // 16 KiB (hist aliases it)
    if ((int)blockIdx.x < nblk) {
        int* hist = (int*)shbuf;
        for (int i = threadIdx.x; i < nbkt; i += 256) hist[i] = 0;
        __syncthreads();
        int base = blockIdx.x * EBLK;
#pragma unroll 4
        for (int k = 0; k < EBLK / 256; ++k) {
            int i = base + k * 256 + threadIdx.x;
            if (i < E) atomicAdd(&hist[dst[i] >> BKB], 1);
        }
        __syncthreads();
        for (int i = threadIdx.x; i < nbkt; i += 256)
            counts[(size_t)i * nblk + blockIdx.x] = hist[i];
        return;
    }
    for (int i = threadIdx.x; i < DEMB * DHID / 2; i += 256) {
        float2 w = reinterpret_cast<const float2*>(W1)[i];
        shbuf[i] = pack2(w.x, w.y);
    }
    __syncthreads();
    int gb = blockIdx.x - nblk;
    int row = gb * GROWS + (threadIdx.x >> 4);
    int cp4 = threadIdx.x & 15;                     // cols 4*cp4 .. 4*cp4+3
    if (row >= V) return;
    const float4* t4 = reinterpret_cast<const float4*>(T + (size_t)row * DEMB);
    float a0 = 0.f, a1 = 0.f, a2 = 0.f, a3 = 0.f;
#pragma unroll 4
    for (int k4 = 0; k4 < DEMB / 4; ++k4) {
        float4 t = t4[k4];
        const uint2* wb = reinterpret_cast<const uint2*>(&shbuf[(k4 * 4) * 32 + cp4 * 2]);
        float f0, f1, f2, f3;
        uint2 w;
        w = wb[0];  bf2x(w.x, f0, f1); bf2x(w.y, f2, f3);
        a0 = fmaf(t.x, f0, a0); a1 = fmaf(t.x, f1, a1); a2 = fmaf(t.x, f2, a2); a3 = fmaf(t.x, f3, a3);
        w = wb[16]; bf2x(w.x, f0, f1); bf2x(w.y, f2, f3);
        a0 = fmaf(t.y, f0, a0); a1 = fmaf(t.y, f1, a1); a2 = fmaf(t.y, f2, a2); a3 = fmaf(t.y, f3, a3);
        w = wb[32]; bf2x(w.x, f0, f1); bf2x(w.y, f2, f3);
        a0 = fmaf(t.z, f0, a0); a1 = fmaf(t.z, f1, a1); a2 = fmaf(t.z, f2, a2); a3 = fmaf(t.z, f3, a3);
        w = wb[48]; bf2x(w.x, f0, f1); bf2x(w.y, f2, f3);
        a0 = fmaf(t.w, f0, a0); a1 = fmaf(t.w, f1, a1); a2 = fmaf(t.w, f2, a2); a3 = fmaf(t.w, f3, a3);
    }
    uint2 o;
    o.x = f2h2(a0, a1);                             // fp16 table
    o.y = f2h2(a2, a3);
    *reinterpret_cast<uint2*>(TW + (size_t)row * DHID + cp4 * 4) = o;
}

// ---------------------------------------------------------------------------
// K2a: one block per bucket — parallel exclusive scan of counts[b][0..nblk)
__global__ __launch_bounds__(256) void passB1(int* __restrict__ counts, int nblk,
                                              int* __restrict__ btot) {
    __shared__ int sh[256];
    int b = blockIdx.x, t = threadIdx.x;
    int* p = counts + (size_t)b * nblk;
    int v = (t < nblk) ? p[t] : 0;
    sh[t] = v;
    __syncthreads();
    for (int off = 1; off < 256; off <<= 1) {
        int u = (t >= off) ? sh[t - off] : 0;
        __syncthreads();
        sh[t] += u;
        __syncthreads();
    }
    if (t < nblk) p[t] = sh[t] - v;        // exclusive
    if (t == 255) btot[b] = sh[255];
}

// K2b: single block — scan bucket totals -> rowptr (rowptr[nbkt] = E).
__global__ __launch_bounds__(1024) void passB2(const int* __restrict__ btot, int nbkt,
                                               int* __restrict__ rowptr) {
    __shared__ int tot[1024];
    int t = threadIdx.x;
    int v = (t < nbkt) ? btot[t] : 0;
    tot[t] = v;
    __syncthreads();
    for (int off = 1; off < 1024; off <<= 1) {
        int u = (t >= off) ? tot[t - off] : 0;
        __syncthreads();
        tot[t] += u;
        __syncthreads();
    }
    if (t < nbkt) rowptr[t] = tot[t] - v;
    if (t == nbkt - 1) rowptr[nbkt] = tot[t];
}

// ---------------------------------------------------------------------------
// K3: role split.
//   blocks [0, nblk)  : passC scatter — bbuf[slot] = src | (dst&127)<<17
//   blocks [nblk, ..) : emb_bag UNSCALED: h0[n] = (1/BAG) * sum_j tableW[...]
__global__ __launch_bounds__(256) void passC_bag(const int* __restrict__ src,
                                                 const int* __restrict__ dst, int E,
                                                 const int* __restrict__ counts, int nblk,
                                                 const int* __restrict__ rowptr, int nbkt,
                                                 u32* __restrict__ bbuf,
                                                 const int* __restrict__ idx,
                                                 const u16* __restrict__ TW,
                                                 u16* __restrict__ h0, int n) {
    if ((int)blockIdx.x < nblk) {
        __shared__ int hist[MAXBKT];
        __shared__ int off0[MAXBKT];
        int blk = blockIdx.x;
        for (int i = threadIdx.x; i < nbkt; i += 256) {
            hist[i] = 0;
            off0[i] = rowptr[i] + counts[(size_t)i * nblk + blk];
        }
        __syncthreads();
        int base = blk * EBLK;
#pragma unroll 4
        for (int k = 0; k < EBLK / 256; ++k) {
            int i = base + k * 256 + threadIdx.x;
            if (i < E) {
                int d = dst[i], s = src[i];
                int bk = d >> BKB;
                int l = atomicAdd(&hist[bk], 1);
                bbuf[off0[bk] + l] = (u32)s | ((u32)(d & (BKN - 1)) << 17);
            }
        }
        return;
    }
    int t = (blockIdx.x - nblk) * 256 + threadIdx.x;
    int node = t >> 3, d8 = t & 7;
    if (node >= n) return;
    const int* bi = idx + (size_t)node * BAG;
    uint4 acc = make_uint4(0u, 0u, 0u, 0u);
#pragma unroll
    for (int j = 0; j < BAG; ++j) {
        uint4 v = *reinterpret_cast<const uint4*>(TW + (size_t)bi[j] * DHID + d8 * 8);
        acc = hadd2u4(acc, v);
    }
    const __half2 s2 = __floats2half2_rn(0.1f, 0.1f);   // 1/BAG
    acc.x = hmul2u(acc.x, s2);
    acc.y = hmul2u(acc.y, s2);
    acc.z = hmul2u(acc.z, s2);
    acc.w = hmul2u(acc.w, s2);
    *reinterpret_cast<uint4*>(h0 + (size_t)node * DHID + d8 * 8) = acc;
}

// ---------------------------------------------------------------------------
// K4: adj_build — one block per 128-node bucket. LDS scatter classified by
// src range (3 segments x 32 slots per node), occupied-slot dump, per-range
// degree int4 emit, and h0 *= dinv (fp16, in place).
__global__ __launch_bounds__(256) void adj_build(const u32* __restrict__ bbuf,
                                                 const int* __restrict__ rowptr,
                                                 int* __restrict__ adj,
                                                 int* __restrict__ degr,
                                                 u16* __restrict__ h0, int n,
                                                 int t1, int t2) {
    __shared__ int cnt[NR][BKN];                    // 1.5 KiB
    __shared__ __align__(16) int adjS[BKN * ROWI];  // 48 KiB
    const int b = blockIdx.x, tid = threadIdx.x;
    for (int i = tid; i < NR * BKN; i += 256) ((int*)cnt)[i] = 0;
    __syncthreads();
    int s0 = rowptr[b], s1 = rowptr[b + 1];
    for (int i = s0 + tid; i < s1; i += 256) {
        u32 v = bbuf[i];
        int s = (int)(v & 0x1FFFF);
        int dl = v >> 17;
        int r = (s >= t1) + (s >= t2);
        int slot = atomicAdd(&cnt[r][dl], 1);
        if (slot < CAPR) adjS[dl * ROWI + r * CAPR + slot] = s;
    }
    __syncthreads();
    const int base = b * BKN;
    int nn = n - base; if (nn > BKN) nn = BKN;
    // dump occupied int4 slots: 24 int4 per node (3 ranges x 8)
    int tot4 = nn * (ROWI / 4);
    int4* gout = reinterpret_cast<int4*>(adj + (size_t)base * ROWI);
    const int4* lin = reinterpret_cast<const int4*>(adjS);
    for (int i = tid; i < tot4; i += 256) {
        int row = i / (ROWI / 4), q = i % (ROWI / 4);
        int r = q >> 3, s = q & 7;
        if (s * 4 < cnt[r][row]) gout[i] = lin[i];
    }
    // degr int4 + h0 scale: 2 threads per row
    int row = tid >> 1, half = tid & 1;
    int node = base + row;
    if (node < n) {
        int c0 = cnt[0][row]; if (c0 > CAPR) c0 = CAPR;
        int c1 = cnt[1][row]; if (c1 > CAPR) c1 = CAPR;
        int c2 = cnt[2][row]; if (c2 > CAPR) c2 = CAPR;
        int dc = cnt[0][row] + cnt[1][row] + cnt[2][row];
        if (half == 0)
            *reinterpret_cast<int4*>(degr + (size_t)node * 4) = make_int4(c0, c1, c2, dc);
        float di = rsqrtf((float)(dc + 1));
        __half2 di2 = __floats2half2_rn(di, di);
        uint4* hp = reinterpret_cast<uint4*>(h0 + (size_t)node * DHID + half * 32);
#pragma unroll
        for (int q = 0; q < 4; ++q) {
            uint4 v = hp[q];
            v.x = hmul2u(v.x, di2);
            v.y = hmul2u(v.y, di2);
            v.z = hmul2u(v.z, di2);
            v.w = hmul2u(v.w, di2);
            hp[q] = v;
        }
    }
}

// ---------------------------------------------------------------------------
// range-phased gather accumulate: 8 lanes per node, fp16 packed adds.
__device__ __forceinline__ uint4 gather_ranges(const u16* __restrict__ tab,
                                               const int* __restrict__ ap,
                                               int4 d3, int lane_off, uint4 acc) {
#pragma unroll
    for (int r = 0; r < NR; ++r) {
        int dr = (r == 0) ? d3.x : (r == 1) ? d3.y : d3.z;
        const int* seg = ap + r * CAPR;
        const int4* seg4 = reinterpret_cast<const int4*>(seg);
        int k = 0;
        for (; k + 8 <= dr; k += 8) {
            int4 s0 = seg4[k >> 2], s1 = seg4[(k >> 2) + 1];
            uint4 v0 = *reinterpret_cast<const uint4*>(tab + (size_t)s0.x * DHID + lane_off);
            uint4 v1 = *reinterpret_cast<const uint4*>(tab + (size_t)s0.y * DHID + lane_off);
            uint4 v2 = *reinterpret_cast<const uint4*>(tab + (size_t)s0.z * DHID + lane_off);
            uint4 v3 = *reinterpret_cast<const uint4*>(tab + (size_t)s0.w * DHID + lane_off);
            uint4 v4 = *reinterpret_cast<const uint4*>(tab + (size_t)s1.x * DHID + lane_off);
            uint4 v5 = *reinterpret_cast<const uint4*>(tab + (size_t)s1.y * DHID + lane_off);
            uint4 v6 = *reinterpret_cast<const uint4*>(tab + (size_t)s1.z * DHID + lane_off);
            uint4 v7 = *reinterpret_cast<const uint4*>(tab + (size_t)s1.w * DHID + lane_off);
            v0 = hadd2u4(v0, v1); v2 = hadd2u4(v2, v3);
            v4 = hadd2u4(v4, v5); v6 = hadd2u4(v6, v7);
            v0 = hadd2u4(v0, v2); v4 = hadd2u4(v4, v6);
            acc = hadd2u4(acc, hadd2u4(v0, v4));
        }
        for (; k + 4 <= dr; k += 4) {
            int4 s0 = seg4[k >> 2];
            uint4 v0 = *reinterpret_cast<const uint4*>(tab + (size_t)s0.x * DHID + lane_off);
            uint4 v1 = *reinterpret_cast<const uint4*>(tab + (size_t)s0.y * DHID + lane_off);
            uint4 v2 = *reinterpret_cast<const uint4*>(tab + (size_t)s0.z * DHID + lane_off);
            uint4 v3 = *reinterpret_cast<const uint4*>(tab + (size_t)s0.w * DHID + lane_off);
            v0 = hadd2u4(v0, v1); v2 = hadd2u4(v2, v3);
            acc = hadd2u4(acc, hadd2u4(v0, v2));
        }
        for (; k < dr; ++k) {
            uint4 v = *reinterpret_cast<const uint4*>(tab + (size_t)seg[k] * DHID + lane_off);
            acc = hadd2u4(acc, v);
        }
    }
    return acc;
}

// ---------------------------------------------------------------------------
// conv1mm: fused gather-conv1 (relu) + gemm_h. Range-phased gather;
// gemm via 8-lane shuffle broadcast. hcat fp16 INTERLEAVED.
__global__ __launch_bounds__(256) void conv1mm(const u16* __restrict__ h0,
                                               const int* __restrict__ degr,
                                               const int* __restrict__ adj,
                                               const float* __restrict__ b1,
                                               const float* __restrict__ Wmu,
                                               const float* __restrict__ Wls,
                                               u16* __restrict__ hcat, int n) {
    __shared__ u16 Wp[DHID * DHID];     // 8 KiB, bf16, permuted [k][p]
    for (int i = threadIdx.x; i < DHID * DHID; i += 256) {
        int k = i >> 6, p = i & 63;
        int j = p >> 3, c = p & 7;
        float w = (c < 4) ? Wmu[k * DOUT + j * 4 + c] : Wls[k * DOUT + j * 4 + (c - 4)];
        Wp[i] = f2bf(w);
    }
    __syncthreads();
    int t = blockIdx.x * 256 + threadIdx.x;
    int node = t >> 3, d8 = t & 7;
    if (node >= n) return;
    int4 d3 = *reinterpret_cast<const int4*>(degr + (size_t)node * 4);
    int dc = d3.w;
    const int* ap = adj + (size_t)node * ROWI;
    uint4 acc = *reinterpret_cast<const uint4*>(h0 + (size_t)node * DHID + d8 * 8);  // self
    acc = gather_ranges(h0, ap, d3, d8 * 8, acc);
    float di = rsqrtf((float)(dc + 1));
    float4 b0 = *reinterpret_cast<const float4*>(b1 + d8 * 8);
    float4 b4 = *reinterpret_cast<const float4*>(b1 + d8 * 8 + 4);
    float2 q0 = h2f2(acc.x), q1 = h2f2(acc.y), q2 = h2f2(acc.z), q3 = h2f2(acc.w);
    float pr[8];
    pr[0] = fmaxf(fmaf(di, q0.x, b0.x), 0.f);
    pr[1] = fmaxf(fmaf(di, q0.y, b0.y), 0.f);
    pr[2] = fmaxf(fmaf(di, q1.x, b0.z), 0.f);
    pr[3] = fmaxf(fmaf(di, q1.y, b0.w), 0.f);
    pr[4] = fmaxf(fmaf(di, q2.x, b4.x), 0.f);
    pr[5] = fmaxf(fmaf(di, q2.y, b4.y), 0.f);
    pr[6] = fmaxf(fmaf(di, q3.x, b4.z), 0.f);
    pr[7] = fmaxf(fmaf(di, q3.y, b4.w), 0.f);
    float oa[8] = {0.f, 0.f, 0.f, 0.f, 0.f, 0.f, 0.f, 0.f};
#pragma unroll
    for (int kk = 0; kk < DHID; ++kk) {
        float hv = __shfl(pr[kk & 7], kk >> 3, 8);
        uint4 wv = *reinterpret_cast<const uint4*>(&Wp[kk * DHID + d8 * 8]);
        float f0, f1;
        bf2x(wv.x, f0, f1); oa[0] = fmaf(hv, f0, oa[0]); oa[1] = fmaf(hv, f1, oa[1]);
        bf2x(wv.y, f0, f1); oa[2] = fmaf(hv, f0, oa[2]); oa[3] = fmaf(hv, f1, oa[3]);
        bf2x(wv.z, f0, f1); oa[4] = fmaf(hv, f0, oa[4]); oa[5] = fmaf(hv, f1, oa[5]);
        bf2x(wv.w, f0, f1); oa[6] = fmaf(hv, f0, oa[6]); oa[7] = fmaf(hv, f1, oa[7]);
    }
    uint4 o;
    o.x = f2h2(oa[0] * di, oa[1] * di);
    o.y = f2h2(oa[2] * di, oa[3] * di);
    o.z = f2h2(oa[4] * di, oa[5] * di);
    o.w = f2h2(oa[6] * di, oa[7] * di);
    *reinterpret_cast<uint4*>(hcat + (size_t)node * DHID + d8 * 8) = o;
}

// ---------------------------------------------------------------------------
// conv2 + reparameterize: range-phased fp16 packed accumulate.
__global__ void gather_conv2(const u16* __restrict__ hcat, const int* __restrict__ degr,
                             const int* __restrict__ adj,
                             const float* __restrict__ bmu, const float* __restrict__ bls,
                             const float* __restrict__ noise, __half* __restrict__ z, int n) {
    int t = blockIdx.x * blockDim.x + threadIdx.x;
    int node = t >> 3, j = t & 7;
    if (node >= n) return;
    int4 d3 = *reinterpret_cast<const int4*>(degr + (size_t)node * 4);
    int dc = d3.w;
    const int* ap = adj + (size_t)node * ROWI;
    uint4 acc = *reinterpret_cast<const uint4*>(hcat + (size_t)node * DHID + j * 8);  // self
    acc = gather_ranges(hcat, ap, d3, j * 8, acc);
    float di = rsqrtf((float)(dc + 1));
    float2 m01 = h2f2(acc.x), m23 = h2f2(acc.y);
    float2 l01 = h2f2(acc.z), l23 = h2f2(acc.w);
    float4 bm = *reinterpret_cast<const float4*>(bmu + j * 4);
    float4 bl = *reinterpret_cast<const float4*>(bls + j * 4);
    float4 nz = *reinterpret_cast<const float4*>(noise + (size_t)node * DOUT + j * 4);
    float z0 = fmaf(di, m01.x, bm.x) + nz.x * expf(fmaf(di, l01.x, bl.x));
    float z1 = fmaf(di, m01.y, bm.y) + nz.y * expf(fmaf(di, l01.y, bl.y));
    float z2 = fmaf(di, m23.x, bm.z) + nz.z * expf(fmaf(di, l23.x, bl.z));
    float z3 = fmaf(di, m23.y, bm.w) + nz.w * expf(fmaf(di, l23.y, bl.w));
    uint2 o;
    o.x = f2h2(z0, z1);
    o.y = f2h2(z2, z3);
    *reinterpret_cast<uint2*>(z + (size_t)node * DOUT + j * 4) = o;
}

// ---------------------------------------------------------------------------
__global__ void edge_dot(const __half* __restrict__ z, const int* __restrict__ src,
                         const int* __restrict__ dst, float* __restrict__ out, int E) {
    int t = blockIdx.x * blockDim.x + threadIdx.x;
    int e = t >> 2, q = t & 3;
    if (e >= E) return;
    uint4 a = *reinterpret_cast<const uint4*>(z + (size_t)src[e] * DOUT + q * 8);
    uint4 b = *reinterpret_cast<const uint4*>(z + (size_t)dst[e] * DOUT + q * 8);
    float s = 0.f;
    float2 x, y;
    x = h2f2(a.x); y = h2f2(b.x); s += x.x * y.x + x.y * y.y;
    x = h2f2(a.y); y = h2f2(b.y); s += x.x * y.x + x.y * y.y;
    x = h2f2(a.z); y = h2f2(b.z); s += x.x * y.x + x.y * y.y;
    x = h2f2(a.w); y = h2f2(b.w); s += x.x * y.x + x.y * y.y;
    s += __shfl_xor(s, 1);
    s += __shfl_xor(s, 2);
    if (q == 0) out[e] = 1.0f / (1.0f + expf(-s));
}

// ---------------------------------------------------------------------------
extern "C" void kernel_launch(void* const* d_in, const int* in_sizes, int n_in,
                              void* d_out, int out_size, void* d_ws, size_t ws_size,
                              hipStream_t stream) {
    const int*   feat_idx = (const int*)d_in[0];
    const int*   edges    = (const int*)d_in[2];
    const float* table    = (const float*)d_in[3];
    const float* W1       = (const float*)d_in[4];
    const float* b1       = (const float*)d_in[5];
    const float* Wmu      = (const float*)d_in[6];
    const float* bmu      = (const float*)d_in[7];
    const float* Wls      = (const float*)d_in[8];
    const float* bls      = (const float*)d_in[9];
    const float* noise    = (const float*)d_in[10];

    const int N = in_sizes[10] / DOUT;
    const int E = in_sizes[2] / 2;
    const int V = in_sizes[3] / DEMB;

    const int* src = edges;
    const int* dst = edges + E;

    const int NBKT = (N + BKN - 1) / BKN;       // 782
    const int NBLK = (E + EBLK - 1) / EBLK;     // 196 (<= 256)
    const int T1 = (N + NR - 1) / NR;           // src range thresholds
    const int T2 = 2 * T1;

    // --- workspace partition ---
    char* ws = (char*)d_ws;
    size_t off = 0;
    auto alloc = [&](size_t bytes) { char* p = ws + off; off += (bytes + 255) & ~size_t(255); return p; };
    u16*    tableW = (u16*)   alloc((size_t)V * DHID * 2);      //  6.4 MB fp16
    u16*    h0     = (u16*)   alloc((size_t)N * DHID * 2);      // 12.8 MB fp16
    u16*    hcat   = (u16*)   alloc((size_t)N * DHID * 2);      // 12.8 MB fp16
    __half* zbuf   = (__half*)alloc((size_t)N * DOUT * 2);      //  6.4 MB fp16
    int*    adj    = (int*)   alloc((size_t)N * ROWI * 4);      // 38.4 MB (3-segment)
    u32*    bbuf   = (u32*)   alloc((size_t)E * 4);             //  6.4 MB
    int*    counts = (int*)   alloc((size_t)NBKT * NBLK * 4);   //  0.6 MB
    int*    rowptr = (int*)   alloc((size_t)(NBKT + 1) * 4);
    int*    btot   = (int*)   alloc((size_t)NBKT * 4);
    int*    degr   = (int*)   alloc((size_t)N * 4 * 4);         //  1.6 MB int4/node
    (void)ws_size;

    const int B = 256;
    const int nbg = (V + GROWS - 1) / GROWS;          // gemm blocks (16 rows each)
    const int nbe = ((long long)N * 8 + B - 1) / B;   // emb_bag blocks

    // K1: bucket histogram ∥ tableW = emb_table @ W1 (fp16 out)
    histA_gemm<<<NBLK + nbg, B, 0, stream>>>(dst, E, counts, NBLK, NBKT,
                                             table, W1, tableW, V);
    // K2: parallel per-bucket scan, then bucket-total scan -> rowptr
    passB1<<<NBKT, B, 0, stream>>>(counts, NBLK, btot);
    passB2<<<1, 1024, 0, stream>>>(btot, NBKT, rowptr);
    // K3: edge scatter into bucket-major bbuf ∥ emb_bag (unscaled, fp16)
    passC_bag<<<NBLK + nbe, B, 0, stream>>>(src, dst, E, counts, NBLK, rowptr, NBKT,
                                            bbuf, feat_idx, tableW, h0, N);
    // K4: per-bucket LDS adjacency build (src-range segmented) + degr + h0 *= dinv
    adj_build<<<NBKT, B, 0, stream>>>(bbuf, rowptr, adj, degr, h0, N, T1, T2);

    // conv1 (range-phased gather, relu) + gemm_h fused -> interleaved fp16 hcat
    conv1mm<<<(N + 31) / 32, B, 0, stream>>>(h0, degr, adj, b1, Wmu, Wls, hcat, N);

    // conv2 (range-phased gather, fused reparameterize) -> fp16 z
    {
        long long t = (long long)N * 8;
        gather_conv2<<<(unsigned)((t + B - 1) / B), B, 0, stream>>>(hcat, degr, adj,
                                                                    bmu, bls, noise, zbuf, N);
    }
    // decoder
    {
        long long t = (long long)E * 4;
        edge_dot<<<(unsigned)((t + B - 1) / B), B, 0, stream>>>(zbuf, src, dst, (float*)d_out, E);
    }
}

// Round 18
// 189.792 us; speedup vs baseline: 1.1220x; 1.1220x over previous
//
#include <hip/hip_runtime.h>
#include <hip/hip_fp16.h>
#include <math.h>

#define DEMB 128
#define DHID 64
#define DOUT 32
#define BAG  10
#define CAP  64      // per-node adjacency capacity (Poisson(16), P(>64)~1e-20)
#define BKB  7       // fine bucket = dst >> 7 (128 nodes)
#define BKN  128
#define EBLK 8192    // edges per partition block (256 thr x 32); nblk <= 256
#define MAXBKT 1024
#define GROWS 32     // rows per gemm block (fp16 W1 LDS tile, 8 threads/row)

typedef unsigned int   u32;
typedef unsigned short u16;

__device__ __forceinline__ u16 f2bf(float f) {
    union { float f; u32 i; } c; c.f = f;
    u32 r = c.i + 0x7FFFu + ((c.i >> 16) & 1u);
    return (u16)(r >> 16);
}
__device__ __forceinline__ void bf2x(u32 v, float& lo, float& hi) {
    union { u32 i; float f; } a, b;
    a.i = v << 16; b.i = v & 0xFFFF0000u;
    lo = a.f; hi = b.f;
}
__device__ __forceinline__ u32 pack2(float f0, float f1) {
    return (u32)f2bf(f0) | ((u32)f2bf(f1) << 16);
}
// fp16 helpers (packed half2 in u32)
__device__ __forceinline__ float2 h2f2(u32 v) {
    __half2 h; *reinterpret_cast<u32*>(&h) = v;
    return __half22float2(h);
}
__device__ __forceinline__ u32 f2h2(float a, float b) {
    __half2 h = __floats2half2_rn(a, b);
    return *reinterpret_cast<u32*>(&h);
}
__device__ __forceinline__ u32 hadd2u(u32 a, u32 b) {
    __half2 ha, hb;
    *reinterpret_cast<u32*>(&ha) = a;
    *reinterpret_cast<u32*>(&hb) = b;
    __half2 r = __hadd2(ha, hb);
    return *reinterpret_cast<u32*>(&r);
}
__device__ __forceinline__ u32 hmul2u(u32 a, __half2 s) {
    __half2 ha; *reinterpret_cast<u32*>(&ha) = a;
    __half2 r = __hmul2(ha, s);
    return *reinterpret_cast<u32*>(&r);
}
__device__ __forceinline__ uint4 hadd2u4(uint4 a, uint4 b) {
    a.x = hadd2u(a.x, b.x); a.y = hadd2u(a.y, b.y);
    a.z = hadd2u(a.z, b.z); a.w = hadd2u(a.w, b.w);
    return a;
}

// ---------------------------------------------------------------------------
// K1: role split.
//   blocks [0, nblk)  : passA histogram — counts[bucket][blk] via LDS
//   blocks [nblk, ..) : gemm_table — tableW = emb_table @ W1 (fp16 out).
//     W1 staged fp16-packed (16 KiB); 8 cols/thread via ds_read_b128
//     (8 lanes x 16B = all 32 banks once -> conflict-free), 32 rows/block.
__global__ __launch_bounds__(256) void histA_gemm(const int* __restrict__ dst, int E,
                                                  int* __restrict__ counts, int nblk, int nbkt,
                                                  const float* __restrict__ T,
                                                  const float* __restrict__ W1,
                                                  u16* __restrict__ TW, int V) {
    __shared__ u32 shbuf[DEMB * DHID / 2];          // 16 KiB (hist aliases it)
    if ((int)blockIdx.x < nblk) {
        int* hist = (int*)shbuf;
        for (int i = threadIdx.x; i < nbkt; i += 256) hist[i] = 0;
        __syncthreads();
        int base = blockIdx.x * EBLK;
#pragma unroll 4
        for (int k = 0; k < EBLK / 256; ++k) {
            int i = base + k * 256 + threadIdx.x;
            if (i < E) atomicAdd(&hist[dst[i] >> BKB], 1);
        }
        __syncthreads();
        for (int i = threadIdx.x; i < nbkt; i += 256)
            counts[(size_t)i * nblk + blockIdx.x] = hist[i];
        return;
    }
    // stage W1 -> fp16 pairs: shbuf[k*32+cp] = {W1[k][2cp], W1[k][2cp+1]}
    for (int i = threadIdx.x; i < DEMB * DHID / 2; i += 256) {
        float2 w = reinterpret_cast<const float2*>(W1)[i];
        shbuf[i] = f2h2(w.x, w.y);
    }
    __syncthreads();
    int gb = blockIdx.x - nblk;
    int row = gb * GROWS + (threadIdx.x >> 3);      // 32 rows, 8 threads each
    int cp = threadIdx.x & 7;                       // cols 8*cp .. 8*cp+7
    if (row >= V) return;
    const float4* t4 = reinterpret_cast<const float4*>(T + (size_t)row * DEMB);
    float a0 = 0.f, a1 = 0.f, a2 = 0.f, a3 = 0.f;
    float a4 = 0.f, a5 = 0.f, a6 = 0.f, a7 = 0.f;
#pragma unroll 4
    for (int k4 = 0; k4 < DEMB / 4; ++k4) {
        float4 t = t4[k4];                          // broadcast per 8-lane group
#pragma unroll
        for (int kk = 0; kk < 4; ++kk) {
            float tk = (kk == 0) ? t.x : (kk == 1) ? t.y : (kk == 2) ? t.z : t.w;
            uint4 w = *reinterpret_cast<const uint4*>(&shbuf[(k4 * 4 + kk) * 32 + cp * 4]);
            float2 f;
            f = h2f2(w.x); a0 = fmaf(tk, f.x, a0); a1 = fmaf(tk, f.y, a1);
            f = h2f2(w.y); a2 = fmaf(tk, f.x, a2); a3 = fmaf(tk, f.y, a3);
            f = h2f2(w.z); a4 = fmaf(tk, f.x, a4); a5 = fmaf(tk, f.y, a5);
            f = h2f2(w.w); a6 = fmaf(tk, f.x, a6); a7 = fmaf(tk, f.y, a7);
        }
    }
    uint4 o;
    o.x = f2h2(a0, a1);
    o.y = f2h2(a2, a3);
    o.z = f2h2(a4, a5);
    o.w = f2h2(a6, a7);
    *reinterpret_cast<uint4*>(TW + (size_t)row * DHID + cp * 8) = o;
}

// ---------------------------------------------------------------------------
// K2a: one block per bucket — parallel exclusive scan of counts[b][0..nblk)
__global__ __launch_bounds__(256) void passB1(int* __restrict__ counts, int nblk,
                                              int* __restrict__ btot) {
    __shared__ int sh[256];
    int b = blockIdx.x, t = threadIdx.x;
    int* p = counts + (size_t)b * nblk;
    int v = (t < nblk) ? p[t] : 0;
    sh[t] = v;
    __syncthreads();
    for (int off = 1; off < 256; off <<= 1) {
        int u = (t >= off) ? sh[t - off] : 0;
        __syncthreads();
        sh[t] += u;
        __syncthreads();
    }
    if (t < nblk) p[t] = sh[t] - v;        // exclusive
    if (t == 255) btot[b] = sh[255];
}

// K2b: single block — scan bucket totals -> rowptr (rowptr[nbkt] = E).
__global__ __launch_bounds__(1024) void passB2(const int* __restrict__ btot, int nbkt,
                                               int* __restrict__ rowptr) {
    __shared__ int tot[1024];
    int t = threadIdx.x;
    int v = (t < nbkt) ? btot[t] : 0;
    tot[t] = v;
    __syncthreads();
    for (int off = 1; off < 1024; off <<= 1) {
        int u = (t >= off) ? tot[t - off] : 0;
        __syncthreads();
        tot[t] += u;
        __syncthreads();
    }
    if (t < nbkt) rowptr[t] = tot[t] - v;
    if (t == nbkt - 1) rowptr[nbkt] = tot[t];
}

// ---------------------------------------------------------------------------
// K3: role split.
//   blocks [0, nblk)  : passC scatter — bbuf[slot] = src | (dst&127)<<17
//   blocks [nblk, ..) : emb_bag UNSCALED: h0[n] = (1/BAG) * sum_j tableW[...]
__global__ __launch_bounds__(256) void passC_bag(const int* __restrict__ src,
                                                 const int* __restrict__ dst, int E,
                                                 const int* __restrict__ counts, int nblk,
                                                 const int* __restrict__ rowptr, int nbkt,
                                                 u32* __restrict__ bbuf,
                                                 const int* __restrict__ idx,
                                                 const u16* __restrict__ TW,
                                                 u16* __restrict__ h0, int n) {
    if ((int)blockIdx.x < nblk) {
        __shared__ int hist[MAXBKT];
        __shared__ int off0[MAXBKT];
        int blk = blockIdx.x;
        for (int i = threadIdx.x; i < nbkt; i += 256) {
            hist[i] = 0;
            off0[i] = rowptr[i] + counts[(size_t)i * nblk + blk];
        }
        __syncthreads();
        int base = blk * EBLK;
#pragma unroll 4
        for (int k = 0; k < EBLK / 256; ++k) {
            int i = base + k * 256 + threadIdx.x;
            if (i < E) {
                int d = dst[i], s = src[i];
                int bk = d >> BKB;
                int l = atomicAdd(&hist[bk], 1);
                bbuf[off0[bk] + l] = (u32)s | ((u32)(d & (BKN - 1)) << 17);
            }
        }
        return;
    }
    int t = (blockIdx.x - nblk) * 256 + threadIdx.x;
    int node = t >> 3, d8 = t & 7;
    if (node >= n) return;
    const int* bi = idx + (size_t)node * BAG;
    uint4 acc = make_uint4(0u, 0u, 0u, 0u);
#pragma unroll
    for (int j = 0; j < BAG; ++j) {
        uint4 v = *reinterpret_cast<const uint4*>(TW + (size_t)bi[j] * DHID + d8 * 8);
        acc = hadd2u4(acc, v);
    }
    const __half2 s2 = __floats2half2_rn(0.1f, 0.1f);   // 1/BAG
    acc.x = hmul2u(acc.x, s2);
    acc.y = hmul2u(acc.y, s2);
    acc.z = hmul2u(acc.z, s2);
    acc.w = hmul2u(acc.w, s2);
    *reinterpret_cast<uint4*>(h0 + (size_t)node * DHID + d8 * 8) = acc;
}

// ---------------------------------------------------------------------------
// K4: adj_build — one block per 128-node bucket. LDS scatter (LDS atomics),
// dump only occupied int4 slots, degc emit, and h0 *= dinv (fp16, in place).
__global__ __launch_bounds__(256) void adj_build(const u32* __restrict__ bbuf,
                                                 const int* __restrict__ rowptr,
                                                 int* __restrict__ adj,
                                                 int* __restrict__ degc,
                                                 u16* __restrict__ h0, int n) {
    __shared__ int cnt[BKN];
    __shared__ __align__(16) int adjS[BKN * CAP];   // 32 KiB
    const int b = blockIdx.x, tid = threadIdx.x;
    if (tid < BKN) cnt[tid] = 0;
    __syncthreads();
    int s0 = rowptr[b], s1 = rowptr[b + 1];
    for (int i = s0 + tid; i < s1; i += 256) {
        u32 v = bbuf[i];
        int dl = v >> 17;
        int r = atomicAdd(&cnt[dl], 1);
        if (r < CAP) adjS[dl * CAP + r] = (int)(v & 0x1FFFF);
    }
    __syncthreads();
    const int base = b * BKN;
    int nn = n - base; if (nn > BKN) nn = BKN;
    int tot4 = nn * (CAP / 4);
    int4* gout = reinterpret_cast<int4*>(adj + (size_t)base * CAP);
    const int4* lin = reinterpret_cast<const int4*>(adjS);
    for (int i = tid; i < tot4; i += 256) {
        int row = i >> 4, s = i & 15;
        if (s * 4 < cnt[row]) gout[i] = lin[i];    // only occupied slots
    }
    int row = tid >> 1, half = tid & 1;
    int node = base + row;
    if (node < n) {
        int dc = cnt[row];
        if (half == 0) degc[node] = dc;
        float di = rsqrtf((float)(dc + 1));
        __half2 di2 = __floats2half2_rn(di, di);
        uint4* hp = reinterpret_cast<uint4*>(h0 + (size_t)node * DHID + half * 32);
#pragma unroll
        for (int q = 0; q < 4; ++q) {
            uint4 v = hp[q];
            v.x = hmul2u(v.x, di2);
            v.y = hmul2u(v.y, di2);
            v.z = hmul2u(v.z, di2);
            v.w = hmul2u(v.w, di2);
            hp[q] = v;
        }
    }
}

// ---------------------------------------------------------------------------
// conv1mm: fused gather-conv1 (relu) + gemm_h via LDS staging.
// Main loop: fp16 packed accumulate of gathered h0 rows.
// hcat written fp16 INTERLEAVED: slot p=j*8+c: c<4 -> mu[j*4+c], c>=4 -> ls[j*4+c-4].
#define HPAD 68
__global__ __launch_bounds__(256) void conv1mm(const u16* __restrict__ h0,
                                               const int* __restrict__ degc,
                                               const int* __restrict__ adj,
                                               const float* __restrict__ b1,
                                               const float* __restrict__ Wmu,
                                               const float* __restrict__ Wls,
                                               u16* __restrict__ hcat, int n) {
    __shared__ u16   Wp[DHID * DHID];
    __shared__ float hs[32][HPAD];
    for (int i = threadIdx.x; i < DHID * DHID; i += 256) {
        int k = i >> 6, p = i & 63;
        int j = p >> 3, c = p & 7;
        float w = (c < 4) ? Wmu[k * DOUT + j * 4 + c] : Wls[k * DOUT + j * 4 + (c - 4)];
        Wp[i] = f2bf(w);
    }
    int t = blockIdx.x * 256 + threadIdx.x;
    int node = t >> 3, d8 = t & 7;
    int lnode = threadIdx.x >> 3;
    int dc = 0;
    if (node < n) {
        dc = degc[node];
        int deg = dc < CAP ? dc : CAP;
        const int* ap = adj + (size_t)node * CAP;
        // start from self loop row, fp16 packed accumulate
        uint4 acc = *reinterpret_cast<const uint4*>(h0 + (size_t)node * DHID + d8 * 8);
        int k = 0;
        for (; k + 4 <= deg; k += 4) {
            int4 ss = *reinterpret_cast<const int4*>(ap + k);
            uint4 v0 = *reinterpret_cast<const uint4*>(h0 + (size_t)ss.x * DHID + d8 * 8);
            uint4 v1 = *reinterpret_cast<const uint4*>(h0 + (size_t)ss.y * DHID + d8 * 8);
            uint4 v2 = *reinterpret_cast<const uint4*>(h0 + (size_t)ss.z * DHID + d8 * 8);
            uint4 v3 = *reinterpret_cast<const uint4*>(h0 + (size_t)ss.w * DHID + d8 * 8);
            v0 = hadd2u4(v0, v1); v2 = hadd2u4(v2, v3);
            acc = hadd2u4(acc, hadd2u4(v0, v2));
        }
        for (; k < deg; ++k) {
            uint4 v = *reinterpret_cast<const uint4*>(h0 + (size_t)ap[k] * DHID + d8 * 8);
            acc = hadd2u4(acc, v);
        }
        float di = rsqrtf((float)(dc + 1));
        float4 b0 = *reinterpret_cast<const float4*>(b1 + d8 * 8);
        float4 b4 = *reinterpret_cast<const float4*>(b1 + d8 * 8 + 4);
        float2 p0 = h2f2(acc.x), p1 = h2f2(acc.y), p2 = h2f2(acc.z), p3 = h2f2(acc.w);
        float4 o0, o1;
        o0.x = fmaxf(fmaf(di, p0.x, b0.x), 0.f);
        o0.y = fmaxf(fmaf(di, p0.y, b0.y), 0.f);
        o0.z = fmaxf(fmaf(di, p1.x, b0.z), 0.f);
        o0.w = fmaxf(fmaf(di, p1.y, b0.w), 0.f);
        o1.x = fmaxf(fmaf(di, p2.x, b4.x), 0.f);
        o1.y = fmaxf(fmaf(di, p2.y, b4.y), 0.f);
        o1.z = fmaxf(fmaf(di, p3.x, b4.z), 0.f);
        o1.w = fmaxf(fmaf(di, p3.y, b4.w), 0.f);
        *reinterpret_cast<float4*>(&hs[lnode][d8 * 8])     = o0;
        *reinterpret_cast<float4*>(&hs[lnode][d8 * 8 + 4]) = o1;
    }
    __syncthreads();
    if (node >= n) return;
    float acc[8] = {0.f, 0.f, 0.f, 0.f, 0.f, 0.f, 0.f, 0.f};
#pragma unroll 4
    for (int k = 0; k < DHID; ++k) {
        float hv = hs[lnode][k];
        uint4 wv = *reinterpret_cast<const uint4*>(&Wp[k * DHID + d8 * 8]);
        float f0, f1;
        bf2x(wv.x, f0, f1); acc[0] = fmaf(hv, f0, acc[0]); acc[1] = fmaf(hv, f1, acc[1]);
        bf2x(wv.y, f0, f1); acc[2] = fmaf(hv, f0, acc[2]); acc[3] = fmaf(hv, f1, acc[3]);
        bf2x(wv.z, f0, f1); acc[4] = fmaf(hv, f0, acc[4]); acc[5] = fmaf(hv, f1, acc[5]);
        bf2x(wv.w, f0, f1); acc[6] = fmaf(hv, f0, acc[6]); acc[7] = fmaf(hv, f1, acc[7]);
    }
    float di = rsqrtf((float)(dc + 1));
    uint4 o;
    o.x = f2h2(acc[0] * di, acc[1] * di);
    o.y = f2h2(acc[2] * di, acc[3] * di);
    o.z = f2h2(acc[4] * di, acc[5] * di);
    o.w = f2h2(acc[6] * di, acc[7] * di);
    *reinterpret_cast<uint4*>(hcat + (size_t)node * DHID + d8 * 8) = o;
}

// ---------------------------------------------------------------------------
// conv2 + reparameterize: fp16 packed accumulate of interleaved hcat rows.
__global__ void gather_conv2(const u16* __restrict__ hcat, const int* __restrict__ degc,
                             const int* __restrict__ adj,
                             const float* __restrict__ bmu, const float* __restrict__ bls,
                             const float* __restrict__ noise, __half* __restrict__ z, int n) {
    int t = blockIdx.x * blockDim.x + threadIdx.x;
    int node = t >> 3, j = t & 7;
    if (node >= n) return;
    int dc = degc[node];
    int deg = dc < CAP ? dc : CAP;
    const int* ap = adj + (size_t)node * CAP;
    // self loop
    uint4 acc = *reinterpret_cast<const uint4*>(hcat + (size_t)node * DHID + j * 8);
    int k = 0;
    for (; k + 4 <= deg; k += 4) {
        int4 ss = *reinterpret_cast<const int4*>(ap + k);
        uint4 v0 = *reinterpret_cast<const uint4*>(hcat + (size_t)ss.x * DHID + j * 8);
        uint4 v1 = *reinterpret_cast<const uint4*>(hcat + (size_t)ss.y * DHID + j * 8);
        uint4 v2 = *reinterpret_cast<const uint4*>(hcat + (size_t)ss.z * DHID + j * 8);
        uint4 v3 = *reinterpret_cast<const uint4*>(hcat + (size_t)ss.w * DHID + j * 8);
        v0 = hadd2u4(v0, v1); v2 = hadd2u4(v2, v3);
        acc = hadd2u4(acc, hadd2u4(v0, v2));
    }
    for (; k < deg; ++k) {
        uint4 v = *reinterpret_cast<const uint4*>(hcat + (size_t)ap[k] * DHID + j * 8);
        acc = hadd2u4(acc, v);
    }
    float di = rsqrtf((float)(dc + 1));
    float2 m01 = h2f2(acc.x), m23 = h2f2(acc.y);
    float2 l01 = h2f2(acc.z), l23 = h2f2(acc.w);
    float4 bm = *reinterpret_cast<const float4*>(bmu + j * 4);
    float4 bl = *reinterpret_cast<const float4*>(bls + j * 4);
    float4 nz = *reinterpret_cast<const float4*>(noise + (size_t)node * DOUT + j * 4);
    float z0 = fmaf(di, m01.x, bm.x) + nz.x * expf(fmaf(di, l01.x, bl.x));
    float z1 = fmaf(di, m01.y, bm.y) + nz.y * expf(fmaf(di, l01.y, bl.y));
    float z2 = fmaf(di, m23.x, bm.z) + nz.z * expf(fmaf(di, l23.x, bl.z));
    float z3 = fmaf(di, m23.y, bm.w) + nz.w * expf(fmaf(di, l23.y, bl.w));
    uint2 o;
    o.x = f2h2(z0, z1);
    o.y = f2h2(z2, z3);
    *reinterpret_cast<uint2*>(z + (size_t)node * DOUT + j * 4) = o;
}

// ---------------------------------------------------------------------------
__global__ void edge_dot(const __half* __restrict__ z, const int* __restrict__ src,
                         const int* __restrict__ dst, float* __restrict__ out, int E) {
    int t = blockIdx.x * blockDim.x + threadIdx.x;
    int e = t >> 2, q = t & 3;
    if (e >= E) return;
    uint4 a = *reinterpret_cast<const uint4*>(z + (size_t)src[e] * DOUT + q * 8);
    uint4 b = *reinterpret_cast<const uint4*>(z + (size_t)dst[e] * DOUT + q * 8);
    float s = 0.f;
    float2 x, y;
    x = h2f2(a.x); y = h2f2(b.x); s += x.x * y.x + x.y * y.y;
    x = h2f2(a.y); y = h2f2(b.y); s += x.x * y.x + x.y * y.y;
    x = h2f2(a.z); y = h2f2(b.z); s += x.x * y.x + x.y * y.y;
    x = h2f2(a.w); y = h2f2(b.w); s += x.x * y.x + x.y * y.y;
    s += __shfl_xor(s, 1);
    s += __shfl_xor(s, 2);
    if (q == 0) out[e] = 1.0f / (1.0f + expf(-s));
}

// ---------------------------------------------------------------------------
extern "C" void kernel_launch(void* const* d_in, const int* in_sizes, int n_in,
                              void* d_out, int out_size, void* d_ws, size_t ws_size,
                              hipStream_t stream) {
    const int*   feat_idx = (const int*)d_in[0];
    const int*   edges    = (const int*)d_in[2];
    const float* table    = (const float*)d_in[3];
    const float* W1       = (const float*)d_in[4];
    const float* b1       = (const float*)d_in[5];
    const float* Wmu      = (const float*)d_in[6];
    const float* bmu      = (const float*)d_in[7];
    const float* Wls      = (const float*)d_in[8];
    const float* bls      = (const float*)d_in[9];
    const float* noise    = (const float*)d_in[10];

    const int N = in_sizes[10] / DOUT;
    const int E = in_sizes[2] / 2;
    const int V = in_sizes[3] / DEMB;

    const int* src = edges;
    const int* dst = edges + E;

    const int NBKT = (N + BKN - 1) / BKN;       // 782
    const int NBLK = (E + EBLK - 1) / EBLK;     // 196 (<= 256)

    // --- workspace partition ---
    char* ws = (char*)d_ws;
    size_t off = 0;
    auto alloc = [&](size_t bytes) { char* p = ws + off; off += (bytes + 255) & ~size_t(255); return p; };
    u16*    tableW = (u16*)   alloc((size_t)V * DHID * 2);      //  6.4 MB fp16
    u16*    h0     = (u16*)   alloc((size_t)N * DHID * 2);      // 12.8 MB fp16
    u16*    hcat   = (u16*)   alloc((size_t)N * DHID * 2);      // 12.8 MB fp16
    __half* zbuf   = (__half*)alloc((size_t)N * DOUT * 2);      //  6.4 MB fp16
    int*    adj    = (int*)   alloc((size_t)N * CAP * 4);       // 25.6 MB
    u32*    bbuf   = (u32*)   alloc((size_t)E * 4);             //  6.4 MB
    int*    counts = (int*)   alloc((size_t)NBKT * NBLK * 4);   //  0.6 MB
    int*    rowptr = (int*)   alloc((size_t)(NBKT + 1) * 4);
    int*    btot   = (int*)   alloc((size_t)NBKT * 4);
    int*    degc   = (int*)   alloc((size_t)N * 4);
    (void)ws_size;

    const int B = 256;
    const int nbg = (V + GROWS - 1) / GROWS;          // gemm blocks (32 rows each)
    const int nbe = ((long long)N * 8 + B - 1) / B;   // emb_bag blocks

    // K1: bucket histogram ∥ tableW = emb_table @ W1 (fp16 out)
    histA_gemm<<<NBLK + nbg, B, 0, stream>>>(dst, E, counts, NBLK, NBKT,
                                             table, W1, tableW, V);
    // K2: parallel per-bucket scan, then bucket-total scan -> rowptr
    passB1<<<NBKT, B, 0, stream>>>(counts, NBLK, btot);
    passB2<<<1, 1024, 0, stream>>>(btot, NBKT, rowptr);
    // K3: edge scatter into bucket-major bbuf ∥ emb_bag (unscaled, fp16)
    passC_bag<<<NBLK + nbe, B, 0, stream>>>(src, dst, E, counts, NBLK, rowptr, NBKT,
                                            bbuf, feat_idx, tableW, h0, N);
    // K4: per-bucket LDS adjacency build + degc + h0 *= dinv (fp16)
    adj_build<<<NBKT, B, 0, stream>>>(bbuf, rowptr, adj, degc, h0, N);

    // conv1 (gather, relu) + gemm_h fused -> interleaved fp16 hcat
    conv1mm<<<(N + 31) / 32, B, 0, stream>>>(h0, degc, adj, b1, Wmu, Wls, hcat, N);

    // conv2 (gather, fused reparameterize) -> fp16 z
    {
        long long t = (long long)N * 8;
        gather_conv2<<<(unsigned)((t + B - 1) / B), B, 0, stream>>>(hcat, degc, adj,
                                                                    bmu, bls, noise, zbuf, N);
    }
    // decoder
    {
        long long t = (long long)E * 4;
        edge_dot<<<(unsigned)((t + B - 1) / B), B, 0, stream>>>(zbuf, src, dst, (float*)d_out, E);
    }
}